// Round 7
// baseline (192.516 us; speedup 1.0000x reference)
//
#include <hip/hip_runtime.h>
#include <math.h>

#define DD 32
#define HH 128

typedef __attribute__((ext_vector_type(8))) __bf16 bf16x8;
typedef __attribute__((ext_vector_type(4))) float  f32x4;
typedef __attribute__((ext_vector_type(2))) int    i32x2;

// ---- ws layout (float offsets) -------------------------------------------
// [0,128)        c0    : vb1[kh] + t * vW1[32][kh]
// [128,320)      tripg : 6 x 32 raw triple gradients
// [320,16704)    frags : 64 MFMA weight fragments, each 64 lanes x 16B
#define WS_C0    0
#define WS_TRIPG 128
#define WS_FRAG  320
#define FW1H 0
#define FW1L 8
#define FW2H 16
#define FW2L 24
#define FP1H 32
#define FP1L 40
#define FPTH 48
#define FPTL 56

__device__ __forceinline__ f32x4 mfma16(bf16x8 a, bf16x8 b, f32x4 c) {
    return __builtin_amdgcn_mfma_f32_16x16x32_bf16(a, b, c, 0, 0, 0);
}

__device__ __forceinline__ float fast_tanh(float x) {
    float ax = fabsf(x);
    float e  = __expf(-2.0f * ax);
    float r  = __fdividef(1.0f - e, 1.0f + e);
    return copysignf(r, x);
}

// sech^2(x) = 4 e^{-2|x|} / (1 + e^{-2|x|})^2
__device__ __forceinline__ float sech2(float x) {
    float ax  = fabsf(x);
    float e   = __expf(-2.0f * ax);
    float inv = __fdividef(1.0f, 1.0f + e);
    return 4.0f * e * inv * inv;
}

// ---- Prep: build c0 and all weight MFMA fragments in ws -------------------
// kappa conventions (A and B share it -> correct for any hw k-ordering):
//   GEMM1 (K=32):  kappa1(g,i) = 8g + i
//   GEMM2 (K=128, step s): kappa2(g,s,i) = 16*(2s + (i>>2)) + 4g + (i&3)
__global__ void k_prep(const float* __restrict__ t,
                       const float* __restrict__ vW1,  // (33,128)
                       const float* __restrict__ vb1,  // (128)
                       const float* __restrict__ vW2,  // (128,32)
                       const float* __restrict__ pW1,  // (32,128)
                       float* __restrict__ ws)
{
    int tid = blockIdx.x * 256 + threadIdx.x;
    if (tid < 4096) {
        int f = tid >> 6, l = tid & 63;
        int g = l >> 4, m = l & 15;
        int cls = f >> 4;          // 0:W1-A  1:W2-B  2:P1-A  3:PT-B
        int q = f & 15;
        bool isLo = (q >= 8);
        int idx = q & 7;
        float v[8];
        if (cls == 0 || cls == 2) {
            const float* W = (cls == 0) ? vW1 : pW1;
            int th = idx;          // A value = W^T[kh][j], kh=16th+m, j=8g+i
            #pragma unroll
            for (int i = 0; i < 8; i++)
                v[i] = W[(8 * g + i) * HH + 16 * th + m];
        } else {
            int nt = idx >> 2, s = idx & 3;
            #pragma unroll
            for (int i = 0; i < 8; i++) {
                int kh = 16 * (2 * s + (i >> 2)) + 4 * g + (i & 3);
                v[i] = (cls == 1) ? vW2[kh * DD + nt * 16 + m]
                                  : pW1[(nt * 16 + m) * HH + kh];
            }
        }
        bf16x8 o;
        #pragma unroll
        for (int i = 0; i < 8; i++) {
            __bf16 h = (__bf16)v[i];
            o[i] = isLo ? (__bf16)(v[i] - (float)h) : h;
        }
        *(bf16x8*)(ws + WS_FRAG + (size_t)(f * 64 + l) * 4) = o;
    } else if (tid < 4096 + HH) {
        int k = tid - 4096;
        ws[WS_C0 + k] = vb1[k] + t[0] * vW1[DD * HH + k];
    }
}

// ---- Kernel 1: dz_dt ------------------------------------------------------
// Persist only W1-hi frags (32 VGPR); lo/B/bias frags re-read per tile from
// the L1/L2-hot 32KB table. Prefetch next tile's z during compute.
__global__ __launch_bounds__(256, 4) void k_dzdt(
    const float* __restrict__ z,
    const float* __restrict__ ws,
    const float* __restrict__ vb2,
    float* __restrict__ out,
    int B)
{
    int lane = threadIdx.x & 63;
    int wid  = blockIdx.x * (blockDim.x >> 6) + (threadIdx.x >> 6);
    int nw   = gridDim.x * (blockDim.x >> 6);
    int g = lane >> 4, m = lane & 15;
    const float* fr = ws + WS_FRAG;

    bf16x8 w1h[8];
    #pragma unroll
    for (int q = 0; q < 8; q++)
        w1h[q] = *(const bf16x8*)(fr + (size_t)((FW1H + q) * 64 + lane) * 4);
    float vb20 = vb2[m], vb21 = vb2[16 + m];

    int ntiles = (B + 15) >> 4;
    int tt = wid;
    if (tt >= ntiles) return;
    f32x4 za, zb;
    {
        int zrow = tt * 16 + m; if (zrow >= B) zrow = 0;
        const float* zp = z + (size_t)zrow * DD + 8 * g;
        za = *(const f32x4*)zp; zb = *(const f32x4*)(zp + 4);
    }
    while (true) {
        int tn = tt + nw;
        f32x4 nza, nzb;
        if (tn < ntiles) {          // prefetch next tile (issues before MFMAs)
            int zrow = tn * 16 + m; if (zrow >= B) zrow = 0;
            const float* zp = z + (size_t)zrow * DD + 8 * g;
            nza = *(const f32x4*)zp; nzb = *(const f32x4*)(zp + 4);
        }
        bf16x8 zh, zl;
        #pragma unroll
        for (int i = 0; i < 4; i++) {
            __bf16 h = (__bf16)za[i]; zh[i] = h; zl[i] = (__bf16)(za[i] - (float)h);
        }
        #pragma unroll
        for (int i = 0; i < 4; i++) {
            __bf16 h = (__bf16)zb[i]; zh[4+i] = h; zl[4+i] = (__bf16)(zb[i] - (float)h);
        }

        f32x4 acc1[8];
        #pragma unroll
        for (int th = 0; th < 8; th++) {
            bf16x8 wl = *(const bf16x8*)(fr + (size_t)((FW1L + th) * 64 + lane) * 4);
            f32x4 a = *(const f32x4*)(ws + WS_C0 + 16 * th + 4 * g);
            a = mfma16(w1h[th], zl, a);
            a = mfma16(wl, zh, a);
            a = mfma16(w1h[th], zh, a);
            acc1[th] = a;
        }
        float hv[32];
        #pragma unroll
        for (int th = 0; th < 8; th++) {
            #pragma unroll
            for (int r = 0; r < 4; r++) hv[4 * th + r] = fast_tanh(acc1[th][r]);
        }
        f32x4 acc2[2];
        acc2[0] = (f32x4){vb20, vb20, vb20, vb20};
        acc2[1] = (f32x4){vb21, vb21, vb21, vb21};
        #pragma unroll
        for (int s = 0; s < 4; s++) {
            bf16x8 ah, al;
            #pragma unroll
            for (int i = 0; i < 8; i++) {
                float x = hv[8 * s + i];
                __bf16 h = (__bf16)x; ah[i] = h; al[i] = (__bf16)(x - (float)h);
            }
            #pragma unroll
            for (int nt = 0; nt < 2; nt++) {
                bf16x8 bh = *(const bf16x8*)(fr + (size_t)((FW2H + nt*4 + s) * 64 + lane) * 4);
                bf16x8 bl = *(const bf16x8*)(fr + (size_t)((FW2L + nt*4 + s) * 64 + lane) * 4);
                f32x4 a = acc2[nt];
                a = mfma16(ah, bl, a);
                a = mfma16(al, bh, a);
                a = mfma16(ah, bh, a);
                acc2[nt] = a;
            }
        }
        int rbase = tt * 16;
        #pragma unroll
        for (int nt = 0; nt < 2; nt++) {
            #pragma unroll
            for (int r = 0; r < 4; r++) {
                int row = rbase + 4 * g + r;
                if (row < B) out[(size_t)row * DD + nt * 16 + m] = acc2[nt][r];
            }
        }
        if (tn >= ntiles) break;
        tt = tn; za = nza; zb = nzb;
    }
}

// ---- Kernel 2: pair forces + 6 triple grads -------------------------------
// Each wave owns <=2 tiles; both tiles' perm+z gathers are issued up front
// (deep MLP), then compute+scatter sequentially. Persist only P1-hi frags.
__global__ __launch_bounds__(256, 4) void k_force(
    const float* __restrict__ z,
    const int*   __restrict__ perm,
    const float* __restrict__ ws,
    const float* __restrict__ pb1,
    const float* __restrict__ pW2,
    float* __restrict__ out,
    float* __restrict__ tripg,
    int np, int nwork)
{
    int lane = threadIdx.x & 63;
    int wid  = blockIdx.x * (blockDim.x >> 6) + (threadIdx.x >> 6);
    int nw   = gridDim.x * (blockDim.x >> 6);
    int g = lane >> 4, m = lane & 15;
    const float* fr = ws + WS_FRAG;

    bf16x8 p1h[8];
    #pragma unroll
    for (int q = 0; q < 8; q++)
        p1h[q] = *(const bf16x8*)(fr + (size_t)((FP1H + q) * 64 + lane) * 4);

    int ntiles = (nwork + 15) >> 4;

    for (int base = wid; base < ntiles; base += 2 * nw) {
        int  tl[2]; tl[0] = base; tl[1] = base + nw;
        bool va[2]; va[0] = true; va[1] = (tl[1] < ntiles);
        int ia[2], ib[2];
        #pragma unroll
        for (int sl = 0; sl < 2; sl++) {
            ia[sl] = 0; ib[sl] = 0;
            if (va[sl]) {
                int p = tl[sl] * 16 + m;
                if (p < np) {
                    i32x2 pr = *(const i32x2*)(perm + 2 * p);
                    ia[sl] = pr[0]; ib[sl] = pr[1];
                } else if (p < nwork) {
                    int ti = p - np;
                    int i3 = ti >> 1, r3 = ti & 1;
                    int j3 = r3 + ((r3 >= i3) ? 1 : 0);
                    ia[sl] = perm[2 * np + i3];
                    ib[sl] = perm[2 * np + j3];
                }
            }
        }
        f32x4 xa[2], xb[2], ya[2], yb[2];
        #pragma unroll
        for (int sl = 0; sl < 2; sl++) {
            if (va[sl]) {
                const float* pa = z + (size_t)ia[sl] * DD + 8 * g;
                const float* pb = z + (size_t)ib[sl] * DD + 8 * g;
                xa[sl] = *(const f32x4*)pa; xb[sl] = *(const f32x4*)(pa + 4);
                ya[sl] = *(const f32x4*)pb; yb[sl] = *(const f32x4*)(pb + 4);
            }
        }
        #pragma unroll
        for (int sl = 0; sl < 2; sl++) {
            if (!va[sl]) continue;
            bf16x8 dh, dl;
            #pragma unroll
            for (int i = 0; i < 4; i++) {
                float d = xa[sl][i] - ya[sl][i];
                __bf16 h = (__bf16)d; dh[i] = h; dl[i] = (__bf16)(d - (float)h);
            }
            #pragma unroll
            for (int i = 0; i < 4; i++) {
                float d = xb[sl][i] - yb[sl][i];
                __bf16 h = (__bf16)d; dh[4+i] = h; dl[4+i] = (__bf16)(d - (float)h);
            }
            f32x4 acc1[8];
            #pragma unroll
            for (int th = 0; th < 8; th++) {
                bf16x8 wl = *(const bf16x8*)(fr + (size_t)((FP1L + th) * 64 + lane) * 4);
                f32x4 a = *(const f32x4*)(pb1 + 16 * th + 4 * g);
                a = mfma16(p1h[th], dl, a);
                a = mfma16(wl, dh, a);
                a = mfma16(p1h[th], dh, a);
                acc1[th] = a;
            }
            float sv[32];
            #pragma unroll
            for (int th = 0; th < 8; th++) {
                f32x4 w2q = *(const f32x4*)(pW2 + 16 * th + 4 * g);
                #pragma unroll
                for (int r = 0; r < 4; r++)
                    sv[4 * th + r] = w2q[r] * sech2(acc1[th][r]);
            }
            f32x4 acc2[2];
            acc2[0] = (f32x4){0.f, 0.f, 0.f, 0.f};
            acc2[1] = (f32x4){0.f, 0.f, 0.f, 0.f};
            #pragma unroll
            for (int s = 0; s < 4; s++) {
                bf16x8 ah, al;
                #pragma unroll
                for (int i = 0; i < 8; i++) {
                    float x = sv[8 * s + i];
                    __bf16 h = (__bf16)x; ah[i] = h; al[i] = (__bf16)(x - (float)h);
                }
                #pragma unroll
                for (int nt = 0; nt < 2; nt++) {
                    bf16x8 bh = *(const bf16x8*)(fr + (size_t)((FPTH + nt*4 + s) * 64 + lane) * 4);
                    bf16x8 bl = *(const bf16x8*)(fr + (size_t)((FPTL + nt*4 + s) * 64 + lane) * 4);
                    f32x4 a = acc2[nt];
                    a = mfma16(ah, bl, a);
                    a = mfma16(al, bh, a);
                    a = mfma16(ah, bh, a);
                    acc2[nt] = a;
                }
            }
            int pbase = tl[sl] * 16;
            #pragma unroll
            for (int r = 0; r < 4; r++) {
                int p2 = pbase + 4 * g + r;
                if (p2 < np) {
                    i32x2 pr = *(const i32x2*)(perm + 2 * p2);
                    #pragma unroll
                    for (int nt = 0; nt < 2; nt++) {
                        float v = acc2[nt][r];
                        out[(size_t)pr[0] * DD + nt * 16 + m] -= v;
                        out[(size_t)pr[1] * DD + nt * 16 + m] += v;
                    }
                } else if (p2 < nwork) {
                    int ti = p2 - np;
                    #pragma unroll
                    for (int nt = 0; nt < 2; nt++)
                        tripg[ti * DD + nt * 16 + m] = acc2[nt][r];
                }
            }
        }
    }
}

// ---- Kernel 3: deterministic triple combine -------------------------------
__global__ void k_triple_combine(
    const int*   __restrict__ perm,
    const float* __restrict__ tripg,
    float* __restrict__ out,
    int np)
{
    int tid = threadIdx.x;
    if (tid >= 3 * DD) return;
    int i = tid >> 5, d = tid & (DD - 1);
    int row = perm[2 * np + i];
    float s = tripg[(2 * i) * DD + d] + tripg[(2 * i + 1) * DD + d];
    out[(size_t)row * DD + d] -= 2.0f * s;
}

extern "C" void kernel_launch(void* const* d_in, const int* in_sizes, int n_in,
                              void* d_out, int out_size, void* d_ws, size_t ws_size,
                              hipStream_t stream) {
    const float* t    = (const float*)d_in[0];
    const float* z    = (const float*)d_in[1];
    const int*   perm = (const int*)  d_in[2];
    const float* vW1  = (const float*)d_in[3];
    const float* vb1  = (const float*)d_in[4];
    const float* vW2  = (const float*)d_in[5];
    const float* vb2  = (const float*)d_in[6];
    const float* pW1  = (const float*)d_in[7];
    const float* pb1  = (const float*)d_in[8];
    const float* pW2  = (const float*)d_in[9];
    // d_in[10] = pb2: constant, vanishes under grad — unused.

    float* out = (float*)d_out;
    float* ws  = (float*)d_ws;

    int B = in_sizes[2];
    int np, ntr;
    if ((B & 1) == 0) { np = B / 2;       ntr = 0; }
    else              { np = (B - 3) / 2; ntr = 1; }

    k_prep<<<17, 256, 0, stream>>>(t, vW1, vb1, vW2, pW1, ws);

    // 1024 blocks x 4 waves = 4096 waves = 16 waves/CU (the <=128-VGPR tier)
    k_dzdt<<<1024, 256, 0, stream>>>(z, ws, vb2, out, B);

    int nwork = np + (ntr ? 6 : 0);
    if (nwork > 0) {
        k_force<<<1024, 256, 0, stream>>>(z, perm, ws, pb1, pW2, out,
                                          ws + WS_TRIPG, np, nwork);
    }
    if (ntr) {
        k_triple_combine<<<1, 128, 0, stream>>>(perm, ws + WS_TRIPG, out, np);
    }
}

// Round 8
// 99.145 us; speedup vs baseline: 1.9418x; 1.9418x over previous
//
#include <hip/hip_runtime.h>
#include <math.h>

#define DD 32
#define HH 128

typedef __attribute__((ext_vector_type(8))) __bf16 bf16x8;
typedef __attribute__((ext_vector_type(4))) float  f32x4;
typedef __attribute__((ext_vector_type(2))) int    i32x2;

// ---- ws layout (float offsets) -------------------------------------------
// [0,128)        c0    : vb1[kh] + t * vW1[32][kh]
// [128,320)      tripg : 6 x 32 raw triple gradients
// [320,16704)    frags : 64 MFMA weight fragments, each 64 lanes x 16B
#define WS_C0    0
#define WS_TRIPG 128
#define WS_FRAG  320
#define FW1H 0
#define FW1L 8
#define FW2H 16
#define FW2L 24
#define FP1H 32
#define FP1L 40
#define FPTH 48
#define FPTL 56

__device__ __forceinline__ f32x4 mfma16(bf16x8 a, bf16x8 b, f32x4 c) {
    return __builtin_amdgcn_mfma_f32_16x16x32_bf16(a, b, c, 0, 0, 0);
}
__device__ __forceinline__ bf16x8 ldfrag(const float* fr, int f, int lane) {
    return *(const bf16x8*)(fr + (size_t)(f * 64 + lane) * 4);
}

__device__ __forceinline__ float fast_tanh(float x) {
    float ax = fabsf(x);
    float e  = __expf(-2.0f * ax);
    float r  = __fdividef(1.0f - e, 1.0f + e);
    return copysignf(r, x);
}

// sech^2(x) = 4 e^{-2|x|} / (1 + e^{-2|x|})^2
__device__ __forceinline__ float sech2(float x) {
    float ax  = fabsf(x);
    float e   = __expf(-2.0f * ax);
    float inv = __fdividef(1.0f, 1.0f + e);
    return 4.0f * e * inv * inv;
}

// ---- Prep: build c0 and all weight MFMA fragments in ws -------------------
// kappa conventions (A and B share it -> correct for any hw k-ordering):
//   GEMM1 (K=32):  kappa1(g,i) = 8g + i
//   GEMM2 (K=128, step s): kappa2(g,s,i) = 16*(2s + (i>>2)) + 4g + (i&3)
__global__ void k_prep(const float* __restrict__ t,
                       const float* __restrict__ vW1,  // (33,128)
                       const float* __restrict__ vb1,  // (128)
                       const float* __restrict__ vW2,  // (128,32)
                       const float* __restrict__ pW1,  // (32,128)
                       float* __restrict__ ws)
{
    int tid = blockIdx.x * 256 + threadIdx.x;
    if (tid < 4096) {
        int f = tid >> 6, l = tid & 63;
        int g = l >> 4, m = l & 15;
        int cls = f >> 4;          // 0:W1-A  1:W2-B  2:P1-A  3:PT-B
        int q = f & 15;
        bool isLo = (q >= 8);
        int idx = q & 7;
        float v[8];
        if (cls == 0 || cls == 2) {
            const float* W = (cls == 0) ? vW1 : pW1;
            int th = idx;          // A value = W^T[kh][j], kh=16th+m, j=8g+i
            #pragma unroll
            for (int i = 0; i < 8; i++)
                v[i] = W[(8 * g + i) * HH + 16 * th + m];
        } else {
            int nt = idx >> 2, s = idx & 3;
            #pragma unroll
            for (int i = 0; i < 8; i++) {
                int kh = 16 * (2 * s + (i >> 2)) + 4 * g + (i & 3);
                v[i] = (cls == 1) ? vW2[kh * DD + nt * 16 + m]
                                  : pW1[(nt * 16 + m) * HH + kh];
            }
        }
        bf16x8 o;
        #pragma unroll
        for (int i = 0; i < 8; i++) {
            __bf16 h = (__bf16)v[i];
            o[i] = isLo ? (__bf16)(v[i] - (float)h) : h;
        }
        *(bf16x8*)(ws + WS_FRAG + (size_t)(f * 64 + l) * 4) = o;
    } else if (tid < 4096 + HH) {
        int k = tid - 4096;
        ws[WS_C0 + k] = vb1[k] + t[0] * vW1[DD * HH + k];
    }
}

// ---- Kernel 1: dz_dt ------------------------------------------------------
// 32-row tiles (2 subtiles A/B share every frag load). s-pipelined:
// step s computes GEMM1 for th={2s,2s+1}, tanh, then GEMM2 k-slice s.
// No persistent frags -> low regs -> high occupancy, no spills.
__global__ __launch_bounds__(256) void k_dzdt(
    const float* __restrict__ z,
    const float* __restrict__ ws,
    const float* __restrict__ vb2,
    float* __restrict__ out,
    int B)
{
    int lane = threadIdx.x & 63;
    int wid  = blockIdx.x * 4 + (threadIdx.x >> 6);
    int nw   = gridDim.x * 4;
    int g = lane >> 4, m = lane & 15;
    const float* fr = ws + WS_FRAG;

    float vb20 = vb2[m], vb21 = vb2[16 + m];

    int ntiles = (B + 31) >> 5;
    for (int tt = wid; tt < ntiles; tt += nw) {
        int rbase = tt * 32;
        int rA = rbase + m;      if (rA >= B) rA = 0;
        int rB = rbase + 16 + m; if (rB >= B) rB = 0;
        const float* pA = z + (size_t)rA * DD + 8 * g;
        const float* pB = z + (size_t)rB * DD + 8 * g;
        f32x4 zaA = *(const f32x4*)pA, zbA = *(const f32x4*)(pA + 4);
        f32x4 zaB = *(const f32x4*)pB, zbB = *(const f32x4*)(pB + 4);
        bf16x8 zhA, zlA, zhB, zlB;
        #pragma unroll
        for (int i = 0; i < 4; i++) {
            __bf16 h;
            h = (__bf16)zaA[i]; zhA[i]   = h; zlA[i]   = (__bf16)(zaA[i] - (float)h);
            h = (__bf16)zbA[i]; zhA[4+i] = h; zlA[4+i] = (__bf16)(zbA[i] - (float)h);
            h = (__bf16)zaB[i]; zhB[i]   = h; zlB[i]   = (__bf16)(zaB[i] - (float)h);
            h = (__bf16)zbB[i]; zhB[4+i] = h; zlB[4+i] = (__bf16)(zbB[i] - (float)h);
        }

        f32x4 accA0 = (f32x4){vb20, vb20, vb20, vb20};
        f32x4 accA1 = (f32x4){vb21, vb21, vb21, vb21};
        f32x4 accB0 = accA0, accB1 = accA1;

        #pragma unroll
        for (int s = 0; s < 4; s++) {
            bf16x8 w1h0 = ldfrag(fr, FW1H + 2*s,     lane);
            bf16x8 w1l0 = ldfrag(fr, FW1L + 2*s,     lane);
            bf16x8 w1h1 = ldfrag(fr, FW1H + 2*s + 1, lane);
            bf16x8 w1l1 = ldfrag(fr, FW1L + 2*s + 1, lane);
            f32x4 c00 = *(const f32x4*)(ws + WS_C0 + 16*(2*s)     + 4*g);
            f32x4 c01 = *(const f32x4*)(ws + WS_C0 + 16*(2*s + 1) + 4*g);

            f32x4 uA0 = c00, uA1 = c01, uB0 = c00, uB1 = c01;
            uA0 = mfma16(w1h0, zlA, uA0); uA0 = mfma16(w1l0, zhA, uA0); uA0 = mfma16(w1h0, zhA, uA0);
            uA1 = mfma16(w1h1, zlA, uA1); uA1 = mfma16(w1l1, zhA, uA1); uA1 = mfma16(w1h1, zhA, uA1);
            uB0 = mfma16(w1h0, zlB, uB0); uB0 = mfma16(w1l0, zhB, uB0); uB0 = mfma16(w1h0, zhB, uB0);
            uB1 = mfma16(w1h1, zlB, uB1); uB1 = mfma16(w1l1, zhB, uB1); uB1 = mfma16(w1h1, zhB, uB1);

            bf16x8 ahA, alA, ahB, alB;
            #pragma unroll
            for (int i = 0; i < 4; i++) {
                float x; __bf16 h;
                x = fast_tanh(uA0[i]); h = (__bf16)x; ahA[i]   = h; alA[i]   = (__bf16)(x - (float)h);
                x = fast_tanh(uA1[i]); h = (__bf16)x; ahA[4+i] = h; alA[4+i] = (__bf16)(x - (float)h);
                x = fast_tanh(uB0[i]); h = (__bf16)x; ahB[i]   = h; alB[i]   = (__bf16)(x - (float)h);
                x = fast_tanh(uB1[i]); h = (__bf16)x; ahB[4+i] = h; alB[4+i] = (__bf16)(x - (float)h);
            }

            bf16x8 b0h = ldfrag(fr, FW2H + 0*4 + s, lane);
            bf16x8 b0l = ldfrag(fr, FW2L + 0*4 + s, lane);
            bf16x8 b1h = ldfrag(fr, FW2H + 1*4 + s, lane);
            bf16x8 b1l = ldfrag(fr, FW2L + 1*4 + s, lane);
            accA0 = mfma16(ahA, b0l, accA0); accA0 = mfma16(alA, b0h, accA0); accA0 = mfma16(ahA, b0h, accA0);
            accA1 = mfma16(ahA, b1l, accA1); accA1 = mfma16(alA, b1h, accA1); accA1 = mfma16(ahA, b1h, accA1);
            accB0 = mfma16(ahB, b0l, accB0); accB0 = mfma16(alB, b0h, accB0); accB0 = mfma16(ahB, b0h, accB0);
            accB1 = mfma16(ahB, b1l, accB1); accB1 = mfma16(alB, b1h, accB1); accB1 = mfma16(ahB, b1h, accB1);
        }

        #pragma unroll
        for (int r = 0; r < 4; r++) {
            int rowA = rbase + 4*g + r;
            if (rowA < B) {
                out[(size_t)rowA * DD + m]      = accA0[r];
                out[(size_t)rowA * DD + 16 + m] = accA1[r];
            }
            int rowB = rbase + 16 + 4*g + r;
            if (rowB < B) {
                out[(size_t)rowB * DD + m]      = accB0[r];
                out[(size_t)rowB * DD + 16 + m] = accB1[r];
            }
        }
    }
}

// ---- Kernel 2: pair forces + 6 triple grads -------------------------------
// 32-pair tiles: ALL 8 gather loads issued up front (2x MLP), then the same
// s-pipelined GEMM1 -> sech2*pW2 -> GEMM2. perm is a permutation -> pair
// rows disjoint -> plain RMW on out, no atomics.
__global__ __launch_bounds__(256) void k_force(
    const float* __restrict__ z,
    const int*   __restrict__ perm,
    const float* __restrict__ ws,
    const float* __restrict__ pb1,
    const float* __restrict__ pW2,
    float* __restrict__ out,
    float* __restrict__ tripg,
    int np, int nwork)
{
    int lane = threadIdx.x & 63;
    int wid  = blockIdx.x * 4 + (threadIdx.x >> 6);
    int nw   = gridDim.x * 4;
    int g = lane >> 4, m = lane & 15;
    const float* fr = ws + WS_FRAG;

    int ntiles = (nwork + 31) >> 5;
    for (int tt = wid; tt < ntiles; tt += nw) {
        int pbase = tt * 32;
        int iaA = 0, ibA = 0, iaB = 0, ibB = 0;
        {
            int p = pbase + m;
            if (p < np) {
                i32x2 pr = *(const i32x2*)(perm + 2 * p);
                iaA = pr[0]; ibA = pr[1];
            } else if (p < nwork) {
                int ti = p - np;
                int i3 = ti >> 1, r3 = ti & 1;
                int j3 = r3 + ((r3 >= i3) ? 1 : 0);
                iaA = perm[2 * np + i3];
                ibA = perm[2 * np + j3];
            }
            p = pbase + 16 + m;
            if (p < np) {
                i32x2 pr = *(const i32x2*)(perm + 2 * p);
                iaB = pr[0]; ibB = pr[1];
            } else if (p < nwork) {
                int ti = p - np;
                int i3 = ti >> 1, r3 = ti & 1;
                int j3 = r3 + ((r3 >= i3) ? 1 : 0);
                iaB = perm[2 * np + i3];
                ibB = perm[2 * np + j3];
            }
        }
        // issue all 8 gathers before any conversion (MLP)
        const float* gx = z + 8 * g;
        f32x4 xaA = *(const f32x4*)(gx + (size_t)iaA * DD);
        f32x4 xbA = *(const f32x4*)(gx + (size_t)iaA * DD + 4);
        f32x4 yaA = *(const f32x4*)(gx + (size_t)ibA * DD);
        f32x4 ybA = *(const f32x4*)(gx + (size_t)ibA * DD + 4);
        f32x4 xaB = *(const f32x4*)(gx + (size_t)iaB * DD);
        f32x4 xbB = *(const f32x4*)(gx + (size_t)iaB * DD + 4);
        f32x4 yaB = *(const f32x4*)(gx + (size_t)ibB * DD);
        f32x4 ybB = *(const f32x4*)(gx + (size_t)ibB * DD + 4);

        bf16x8 dhA, dlA, dhB, dlB;
        #pragma unroll
        for (int i = 0; i < 4; i++) {
            float d; __bf16 h;
            d = xaA[i] - yaA[i]; h = (__bf16)d; dhA[i]   = h; dlA[i]   = (__bf16)(d - (float)h);
            d = xbA[i] - ybA[i]; h = (__bf16)d; dhA[4+i] = h; dlA[4+i] = (__bf16)(d - (float)h);
            d = xaB[i] - yaB[i]; h = (__bf16)d; dhB[i]   = h; dlB[i]   = (__bf16)(d - (float)h);
            d = xbB[i] - ybB[i]; h = (__bf16)d; dhB[4+i] = h; dlB[4+i] = (__bf16)(d - (float)h);
        }

        f32x4 accA0 = (f32x4){0.f,0.f,0.f,0.f}, accA1 = accA0;
        f32x4 accB0 = accA0, accB1 = accA0;

        #pragma unroll
        for (int s = 0; s < 4; s++) {
            bf16x8 p1h0 = ldfrag(fr, FP1H + 2*s,     lane);
            bf16x8 p1l0 = ldfrag(fr, FP1L + 2*s,     lane);
            bf16x8 p1h1 = ldfrag(fr, FP1H + 2*s + 1, lane);
            bf16x8 p1l1 = ldfrag(fr, FP1L + 2*s + 1, lane);
            f32x4 c00 = *(const f32x4*)(pb1 + 16*(2*s)     + 4*g);
            f32x4 c01 = *(const f32x4*)(pb1 + 16*(2*s + 1) + 4*g);

            f32x4 uA0 = c00, uA1 = c01, uB0 = c00, uB1 = c01;
            uA0 = mfma16(p1h0, dlA, uA0); uA0 = mfma16(p1l0, dhA, uA0); uA0 = mfma16(p1h0, dhA, uA0);
            uA1 = mfma16(p1h1, dlA, uA1); uA1 = mfma16(p1l1, dhA, uA1); uA1 = mfma16(p1h1, dhA, uA1);
            uB0 = mfma16(p1h0, dlB, uB0); uB0 = mfma16(p1l0, dhB, uB0); uB0 = mfma16(p1h0, dhB, uB0);
            uB1 = mfma16(p1h1, dlB, uB1); uB1 = mfma16(p1l1, dhB, uB1); uB1 = mfma16(p1h1, dhB, uB1);

            f32x4 w2q0 = *(const f32x4*)(pW2 + 16*(2*s)     + 4*g);
            f32x4 w2q1 = *(const f32x4*)(pW2 + 16*(2*s + 1) + 4*g);
            bf16x8 ahA, alA, ahB, alB;
            #pragma unroll
            for (int i = 0; i < 4; i++) {
                float x; __bf16 h;
                x = w2q0[i] * sech2(uA0[i]); h = (__bf16)x; ahA[i]   = h; alA[i]   = (__bf16)(x - (float)h);
                x = w2q1[i] * sech2(uA1[i]); h = (__bf16)x; ahA[4+i] = h; alA[4+i] = (__bf16)(x - (float)h);
                x = w2q0[i] * sech2(uB0[i]); h = (__bf16)x; ahB[i]   = h; alB[i]   = (__bf16)(x - (float)h);
                x = w2q1[i] * sech2(uB1[i]); h = (__bf16)x; ahB[4+i] = h; alB[4+i] = (__bf16)(x - (float)h);
            }

            bf16x8 b0h = ldfrag(fr, FPTH + 0*4 + s, lane);
            bf16x8 b0l = ldfrag(fr, FPTL + 0*4 + s, lane);
            bf16x8 b1h = ldfrag(fr, FPTH + 1*4 + s, lane);
            bf16x8 b1l = ldfrag(fr, FPTL + 1*4 + s, lane);
            accA0 = mfma16(ahA, b0l, accA0); accA0 = mfma16(alA, b0h, accA0); accA0 = mfma16(ahA, b0h, accA0);
            accA1 = mfma16(ahA, b1l, accA1); accA1 = mfma16(alA, b1h, accA1); accA1 = mfma16(ahA, b1h, accA1);
            accB0 = mfma16(ahB, b0l, accB0); accB0 = mfma16(alB, b0h, accB0); accB0 = mfma16(ahB, b0h, accB0);
            accB1 = mfma16(ahB, b1l, accB1); accB1 = mfma16(alB, b1h, accB1); accB1 = mfma16(ahB, b1h, accB1);
        }

        // scatter: lane (g,m) holds g[p2][j] for p2 = base+4g+r, j = nt*16+m
        #pragma unroll
        for (int r = 0; r < 4; r++) {
            int p2 = pbase + 4*g + r;
            if (p2 < np) {
                i32x2 pr = *(const i32x2*)(perm + 2 * p2);
                float v0 = accA0[r], v1 = accA1[r];
                out[(size_t)pr[0] * DD + m]      -= v0;
                out[(size_t)pr[0] * DD + 16 + m] -= v1;
                out[(size_t)pr[1] * DD + m]      += v0;
                out[(size_t)pr[1] * DD + 16 + m] += v1;
            } else if (p2 < nwork) {
                int ti = p2 - np;
                tripg[ti * DD + m]      = accA0[r];
                tripg[ti * DD + 16 + m] = accA1[r];
            }
            int p3 = pbase + 16 + 4*g + r;
            if (p3 < np) {
                i32x2 pr = *(const i32x2*)(perm + 2 * p3);
                float v0 = accB0[r], v1 = accB1[r];
                out[(size_t)pr[0] * DD + m]      -= v0;
                out[(size_t)pr[0] * DD + 16 + m] -= v1;
                out[(size_t)pr[1] * DD + m]      += v0;
                out[(size_t)pr[1] * DD + 16 + m] += v1;
            } else if (p3 < nwork) {
                int ti = p3 - np;
                tripg[ti * DD + m]      = accB0[r];
                tripg[ti * DD + 16 + m] = accB1[r];
            }
        }
    }
}

// ---- Kernel 3: deterministic triple combine -------------------------------
__global__ void k_triple_combine(
    const int*   __restrict__ perm,
    const float* __restrict__ tripg,
    float* __restrict__ out,
    int np)
{
    int tid = threadIdx.x;
    if (tid >= 3 * DD) return;
    int i = tid >> 5, d = tid & (DD - 1);
    int row = perm[2 * np + i];
    float s = tripg[(2 * i) * DD + d] + tripg[(2 * i + 1) * DD + d];
    out[(size_t)row * DD + d] -= 2.0f * s;
}

extern "C" void kernel_launch(void* const* d_in, const int* in_sizes, int n_in,
                              void* d_out, int out_size, void* d_ws, size_t ws_size,
                              hipStream_t stream) {
    const float* t    = (const float*)d_in[0];
    const float* z    = (const float*)d_in[1];
    const int*   perm = (const int*)  d_in[2];
    const float* vW1  = (const float*)d_in[3];
    const float* vb1  = (const float*)d_in[4];
    const float* vW2  = (const float*)d_in[5];
    const float* vb2  = (const float*)d_in[6];
    const float* pW1  = (const float*)d_in[7];
    const float* pb1  = (const float*)d_in[8];
    const float* pW2  = (const float*)d_in[9];
    // d_in[10] = pb2: constant, vanishes under grad — unused.

    float* out = (float*)d_out;
    float* ws  = (float*)d_ws;

    int B = in_sizes[2];
    int np, ntr;
    if ((B & 1) == 0) { np = B / 2;       ntr = 0; }
    else              { np = (B - 3) / 2; ntr = 1; }

    k_prep<<<17, 256, 0, stream>>>(t, vW1, vb1, vW2, pW1, ws);

    // 782 blocks = 3128 waves: k_dzdt 6251 tiles -> 2/wave balanced;
    // k_force 3126 tiles -> 1/wave.
    k_dzdt<<<782, 256, 0, stream>>>(z, ws, vb2, out, B);

    int nwork = np + (ntr ? 6 : 0);
    if (nwork > 0) {
        k_force<<<782, 256, 0, stream>>>(z, perm, ws, pb1, pW2, out,
                                         ws + WS_TRIPG, np, nwork);
    }
    if (ntr) {
        k_triple_combine<<<1, 128, 0, stream>>>(perm, ws + WS_TRIPG, out, np);
    }
}

// Round 9
// 70.206 us; speedup vs baseline: 2.7422x; 1.4122x over previous
//
#include <hip/hip_runtime.h>
#include <math.h>

#define DD 32
#define HH 128

typedef __attribute__((ext_vector_type(8))) __bf16 bf16x8;
typedef __attribute__((ext_vector_type(4))) float  f32x4;

// ---- ws layout (float offsets) -------------------------------------------
// [0,128)        c0     : vb1[kh] + t * vW1[32][kh]
// [128,320)      tripg  : 6 x 32 raw triple gradients
// [320,336)      tripS  : 6 src row indices for triple grads (int view)
// [336,16720)    frags  : 64 MFMA weight fragments (16B-aligned)
// [16720, +npart) partner: int per logical row (npart = ntiles*16)
#define WS_C0    0
#define WS_TRIPG 128
#define WS_TRIPS 320
#define WS_FRAG  336
#define WS_PART  16720
#define FW1H 0
#define FW1L 8
#define FW2H 16
#define FW2L 24
#define FP1H 32
#define FP1L 40
#define FPTH 48
#define FPTL 56

// partner encoding: bits[0:30) index, bit30 = zero-force, bit31 = second
#define ENC_ZF  0x40000000u
#define ENC_SEC 0x80000000u

__device__ __forceinline__ f32x4 mfma16(bf16x8 a, bf16x8 b, f32x4 c) {
    return __builtin_amdgcn_mfma_f32_16x16x32_bf16(a, b, c, 0, 0, 0);
}
__device__ __forceinline__ bf16x8 ldfrag(const float* fr, int f, int lane) {
    return *(const bf16x8*)(fr + (size_t)(f * 64 + lane) * 4);
}
__device__ __forceinline__ float fast_tanh(float x) {
    float ax = fabsf(x);
    float e  = __expf(-2.0f * ax);
    float r  = __fdividef(1.0f - e, 1.0f + e);
    return copysignf(r, x);
}
__device__ __forceinline__ float sech2(float x) {
    float ax  = fabsf(x);
    float e   = __expf(-2.0f * ax);
    float inv = __fdividef(1.0f, 1.0f + e);
    return 4.0f * e * inv * inv;
}

// ---- Prep 1: c0 + all weight MFMA fragments (same kappa scheme as R6/R8) --
__global__ void k_prep(const float* __restrict__ t,
                       const float* __restrict__ vW1,  // (33,128)
                       const float* __restrict__ vb1,  // (128)
                       const float* __restrict__ vW2,  // (128,32)
                       const float* __restrict__ pW1,  // (32,128)
                       float* __restrict__ ws)
{
    int tid = blockIdx.x * 256 + threadIdx.x;
    if (tid < 4096) {
        int f = tid >> 6, l = tid & 63;
        int g = l >> 4, m = l & 15;
        int cls = f >> 4;          // 0:W1-A  1:W2-B  2:P1-A  3:PT-B
        int q = f & 15;
        bool isLo = (q >= 8);
        int idx = q & 7;
        float v[8];
        if (cls == 0 || cls == 2) {
            const float* W = (cls == 0) ? vW1 : pW1;
            int th = idx;
            #pragma unroll
            for (int i = 0; i < 8; i++)
                v[i] = W[(8 * g + i) * HH + 16 * th + m];
        } else {
            int nt = idx >> 2, s = idx & 3;
            #pragma unroll
            for (int i = 0; i < 8; i++) {
                int kh = 16 * (2 * s + (i >> 2)) + 4 * g + (i & 3);
                v[i] = (cls == 1) ? vW2[kh * DD + nt * 16 + m]
                                  : pW1[(nt * 16 + m) * HH + kh];
            }
        }
        bf16x8 o;
        #pragma unroll
        for (int i = 0; i < 8; i++) {
            __bf16 h = (__bf16)v[i];
            o[i] = isLo ? (__bf16)(v[i] - (float)h) : h;
        }
        *(bf16x8*)(ws + WS_FRAG + (size_t)(f * 64 + l) * 4) = o;
    } else if (tid < 4096 + HH) {
        int k = tid - 4096;
        ws[WS_C0 + k] = vb1[k] + t[0] * vW1[DD * HH + k];
    }
}

// ---- Prep 2: build partner[] (row-centric pairing) ------------------------
__global__ void k_prep2(const int* __restrict__ perm,
                        unsigned int* __restrict__ partner,
                        int* __restrict__ tripS,
                        int np, int ntr, int B, int npart)
{
    int j = blockIdx.x * 256 + threadIdx.x;
    if (j < np) {
        int a = perm[2 * j], b = perm[2 * j + 1];
        partner[a] = (unsigned int)b;            // first of pair
        partner[b] = (unsigned int)a | ENC_SEC;  // second of pair
    }
    if (j == 0) {
        int base = B;
        if (ntr) {
            // the 3 triple rows: zero pair-force (combine kernel adds it)
            for (int i = 0; i < 3; i++)
                partner[perm[2 * np + i]] = ENC_ZF;
            // 6 extra work items: grad(z[i3] - z[j3])
            for (int ti = 0; ti < 6; ti++) {
                int i3 = ti >> 1, r3 = ti & 1;
                int j3 = r3 + ((r3 >= i3) ? 1 : 0);
                tripS[ti] = perm[2 * np + i3];
                partner[B + ti] = (unsigned int)perm[2 * np + j3];
            }
            base = B + 6;
        }
        for (int q = base; q < npart; q++) partner[q] = ENC_ZF;  // dummies
    }
}

// ---- Main kernel: out[i] = dzdt(z_i) + fs_i * grad_phi(d_i) ---------------
// Per wave: 16 logical rows (one per m). z[i] streamed, z[partner] gathered,
// out streamed. Extras (i >= B) compute raw triple grads into tripg.
__global__ __launch_bounds__(256) void k_main(
    const float* __restrict__ z,
    const float* __restrict__ ws,
    const unsigned int* __restrict__ partner,
    const float* __restrict__ vb2,
    const float* __restrict__ pb1,
    const float* __restrict__ pW2,
    float* __restrict__ out,
    float* __restrict__ tripg,
    int B, int ntiles)
{
    int lane = threadIdx.x & 63;
    int tt   = blockIdx.x * 4 + (threadIdx.x >> 6);
    if (tt >= ntiles) return;
    int g = lane >> 4, m = lane & 15;
    const float* fr = ws + WS_FRAG;
    const int* tripS = (const int*)(ws + WS_TRIPS);

    int rbase = tt * 16;
    int ilog  = rbase + m;

    unsigned int enc = partner[ilog];
    int  pi  = (int)(enc & 0x3FFFFFFFu);
    bool zf  = (enc & ENC_ZF) != 0;
    bool sec = (enc & ENC_SEC) != 0;
    float fs = zf ? 0.f : (sec ? 1.f : -1.f);

    int isrc = ilog;
    if (ilog >= B) {
        int ti = ilog - B;
        isrc = (ti < 6) ? tripS[ti] : 0;
    }

    // stream z[isrc], gather z[pi] (all 4 loads issued before conversions)
    const float* pz = z + (size_t)isrc * DD + 8 * g;
    const float* pp = z + (size_t)pi   * DD + 8 * g;
    f32x4 zi0 = *(const f32x4*)pz, zi1 = *(const f32x4*)(pz + 4);
    f32x4 zp0 = *(const f32x4*)pp, zp1 = *(const f32x4*)(pp + 4);

    bf16x8 zh, zl, dh, dl;
    #pragma unroll
    for (int i = 0; i < 4; i++) {
        __bf16 h;
        h = (__bf16)zi0[i]; zh[i]   = h; zl[i]   = (__bf16)(zi0[i] - (float)h);
        h = (__bf16)zi1[i]; zh[4+i] = h; zl[4+i] = (__bf16)(zi1[i] - (float)h);
        float d;
        d = -fs * (zi0[i] - zp0[i]); h = (__bf16)d; dh[i]   = h; dl[i]   = (__bf16)(d - (float)h);
        d = -fs * (zi1[i] - zp1[i]); h = (__bf16)d; dh[4+i] = h; dl[4+i] = (__bf16)(d - (float)h);
    }

    // ---- net1: dz_dt -------------------------------------------------------
    float vb20 = vb2[m], vb21 = vb2[16 + m];
    f32x4 accv0 = (f32x4){vb20, vb20, vb20, vb20};
    f32x4 accv1 = (f32x4){vb21, vb21, vb21, vb21};
    #pragma unroll 1
    for (int s = 0; s < 4; s++) {
        bf16x8 w1h0 = ldfrag(fr, FW1H + 2*s,     lane);
        bf16x8 w1l0 = ldfrag(fr, FW1L + 2*s,     lane);
        bf16x8 w1h1 = ldfrag(fr, FW1H + 2*s + 1, lane);
        bf16x8 w1l1 = ldfrag(fr, FW1L + 2*s + 1, lane);
        f32x4 u0 = *(const f32x4*)(ws + WS_C0 + 16*(2*s)     + 4*g);
        f32x4 u1 = *(const f32x4*)(ws + WS_C0 + 16*(2*s + 1) + 4*g);
        u0 = mfma16(w1h0, zl, u0); u0 = mfma16(w1l0, zh, u0); u0 = mfma16(w1h0, zh, u0);
        u1 = mfma16(w1h1, zl, u1); u1 = mfma16(w1l1, zh, u1); u1 = mfma16(w1h1, zh, u1);
        bf16x8 ah, al;
        #pragma unroll
        for (int i = 0; i < 4; i++) {
            float x; __bf16 h;
            x = fast_tanh(u0[i]); h = (__bf16)x; ah[i]   = h; al[i]   = (__bf16)(x - (float)h);
            x = fast_tanh(u1[i]); h = (__bf16)x; ah[4+i] = h; al[4+i] = (__bf16)(x - (float)h);
        }
        bf16x8 b0h = ldfrag(fr, FW2H + 0*4 + s, lane);
        bf16x8 b0l = ldfrag(fr, FW2L + 0*4 + s, lane);
        bf16x8 b1h = ldfrag(fr, FW2H + 1*4 + s, lane);
        bf16x8 b1l = ldfrag(fr, FW2L + 1*4 + s, lane);
        accv0 = mfma16(ah, b0l, accv0); accv0 = mfma16(al, b0h, accv0); accv0 = mfma16(ah, b0h, accv0);
        accv1 = mfma16(ah, b1l, accv1); accv1 = mfma16(al, b1h, accv1); accv1 = mfma16(ah, b1h, accv1);
    }

    // ---- net2: grad_phi ----------------------------------------------------
    f32x4 accf0 = (f32x4){0.f,0.f,0.f,0.f}, accf1 = accf0;
    #pragma unroll 1
    for (int s = 0; s < 4; s++) {
        bf16x8 p1h0 = ldfrag(fr, FP1H + 2*s,     lane);
        bf16x8 p1l0 = ldfrag(fr, FP1L + 2*s,     lane);
        bf16x8 p1h1 = ldfrag(fr, FP1H + 2*s + 1, lane);
        bf16x8 p1l1 = ldfrag(fr, FP1L + 2*s + 1, lane);
        f32x4 u0 = *(const f32x4*)(pb1 + 16*(2*s)     + 4*g);
        f32x4 u1 = *(const f32x4*)(pb1 + 16*(2*s + 1) + 4*g);
        u0 = mfma16(p1h0, dl, u0); u0 = mfma16(p1l0, dh, u0); u0 = mfma16(p1h0, dh, u0);
        u1 = mfma16(p1h1, dl, u1); u1 = mfma16(p1l1, dh, u1); u1 = mfma16(p1h1, dh, u1);
        f32x4 w2q0 = *(const f32x4*)(pW2 + 16*(2*s)     + 4*g);
        f32x4 w2q1 = *(const f32x4*)(pW2 + 16*(2*s + 1) + 4*g);
        bf16x8 ah, al;
        #pragma unroll
        for (int i = 0; i < 4; i++) {
            float x; __bf16 h;
            x = w2q0[i] * sech2(u0[i]); h = (__bf16)x; ah[i]   = h; al[i]   = (__bf16)(x - (float)h);
            x = w2q1[i] * sech2(u1[i]); h = (__bf16)x; ah[4+i] = h; al[4+i] = (__bf16)(x - (float)h);
        }
        bf16x8 b0h = ldfrag(fr, FPTH + 0*4 + s, lane);
        bf16x8 b0l = ldfrag(fr, FPTL + 0*4 + s, lane);
        bf16x8 b1h = ldfrag(fr, FPTH + 1*4 + s, lane);
        bf16x8 b1l = ldfrag(fr, FPTL + 1*4 + s, lane);
        accf0 = mfma16(ah, b0l, accf0); accf0 = mfma16(al, b0h, accf0); accf0 = mfma16(ah, b0h, accf0);
        accf1 = mfma16(ah, b1l, accf1); accf1 = mfma16(al, b1h, accf1); accf1 = mfma16(ah, b1h, accf1);
    }

    // ---- write: out row' = dzdt + fs*grad (stream); extras -> tripg --------
    #pragma unroll
    for (int r = 0; r < 4; r++) {
        int rp = rbase + 4 * g + r;
        unsigned int e2 = partner[rp];           // L1-hot (same 16 addrs)
        float fsw = (e2 & ENC_ZF) ? 0.f : ((e2 & ENC_SEC) ? 1.f : -1.f);
        if (rp < B) {
            out[(size_t)rp * DD + m]      = accv0[r] + fsw * accf0[r];
            out[(size_t)rp * DD + 16 + m] = accv1[r] + fsw * accf1[r];
        } else {
            int tw = rp - B;
            if (tw < 6) {
                tripg[tw * DD + m]      = accf0[r];
                tripg[tw * DD + 16 + m] = accf1[r];
            }
        }
    }
}

// ---- Triple combine: out[row] -= 2*(G(i,j1)+G(i,j2)) ----------------------
__global__ void k_triple_combine(
    const int*   __restrict__ perm,
    const float* __restrict__ tripg,
    float* __restrict__ out,
    int np)
{
    int tid = threadIdx.x;
    if (tid >= 3 * DD) return;
    int i = tid >> 5, d = tid & (DD - 1);
    int row = perm[2 * np + i];
    float s = tripg[(2 * i) * DD + d] + tripg[(2 * i + 1) * DD + d];
    out[(size_t)row * DD + d] -= 2.0f * s;
}

extern "C" void kernel_launch(void* const* d_in, const int* in_sizes, int n_in,
                              void* d_out, int out_size, void* d_ws, size_t ws_size,
                              hipStream_t stream) {
    const float* t    = (const float*)d_in[0];
    const float* z    = (const float*)d_in[1];
    const int*   perm = (const int*)  d_in[2];
    const float* vW1  = (const float*)d_in[3];
    const float* vb1  = (const float*)d_in[4];
    const float* vW2  = (const float*)d_in[5];
    const float* vb2  = (const float*)d_in[6];
    const float* pW1  = (const float*)d_in[7];
    const float* pb1  = (const float*)d_in[8];
    const float* pW2  = (const float*)d_in[9];
    // d_in[10] = pb2: constant, vanishes under grad — unused.

    float* out = (float*)d_out;
    float* ws  = (float*)d_ws;

    int B = in_sizes[2];
    int np, ntr;
    if ((B & 1) == 0) { np = B / 2;       ntr = 0; }
    else              { np = (B - 3) / 2; ntr = 1; }

    int nlog   = B + (ntr ? 6 : 0);          // logical rows incl. extras
    int ntiles = (nlog + 15) >> 4;
    int npart  = ntiles * 16;

    unsigned int* partner = (unsigned int*)(ws + WS_PART);
    int*          tripS   = (int*)(ws + WS_TRIPS);

    k_prep<<<17, 256, 0, stream>>>(t, vW1, vb1, vW2, pW1, ws);
    k_prep2<<<(np + 255) / 256, 256, 0, stream>>>(perm, partner, tripS,
                                                  np, ntr, B, npart);
    k_main<<<(ntiles + 3) / 4, 256, 0, stream>>>(z, ws, partner, vb2, pb1,
                                                 pW2, out, ws + WS_TRIPG,
                                                 B, ntiles);
    if (ntr) {
        k_triple_combine<<<1, 128, 0, stream>>>(perm, ws + WS_TRIPG, out, np);
    }
}